// Round 1
// baseline (398.776 us; speedup 1.0000x reference)
//
#include <hip/hip_runtime.h>

#define EPS 1e-9f
constexpr int NN = 131072;
constexpr int CD = 64;
constexpr int KK = 32;
constexpr int BB = 16;

// ---- workspace layout (float offsets) ----
constexpr int WS_ENT  = 0;                    // entropy accumulator (1 float)
constexpr int WS_BACC = 16;                   // bacc[B][K][FP]: f 0..63 = x, 64 px, 65 py, 66 |p|^2, 67 = 1
constexpr int FP      = 72;                   // padded feature count
constexpr int WS_BACC_SZ = BB * KK * FP;      // 36864
constexpr int WS_W1T  = WS_BACC + WS_BACC_SZ; // transposed W1 [j][c]

// ---- output layout (float offsets), tuple order of the reference ----
constexpr int OUT_OUT  = 0;                   // [B,K,C] = 32768
constexpr int OUT_S    = BB * KK * CD;        // s [N,K]
constexpr int OUT_SCAL = OUT_S + NN * KK;     // entropy, diversity, spatial, pruning, sparsity, separation
constexpr int OUT_MU   = OUT_SCAL + 6;        // mu [B,K,2]

// one-time transpose of W1 so columns are contiguous (enables s_load_dwordx16 rows)
__global__ void prep_k(const float* __restrict__ W1, float* __restrict__ ws) {
    int t = blockIdx.x * 256 + threadIdx.x;   // 4096 threads
    int c = t >> 6, j = t & 63;
    ws[WS_W1T + j * 64 + c] = W1[c * 64 + j];
}

// per-node: MLP -> scale/mask -> gumbel -> softmax -> s ; entropy partial
__global__ void node_k(const float* __restrict__ x,
                       const float* __restrict__ u,
                       const float* __restrict__ w1t,
                       const float* __restrict__ b1,
                       const float* __restrict__ W2,
                       const float* __restrict__ b2,
                       const float* __restrict__ scaling,
                       const float* __restrict__ amask,
                       float* __restrict__ s_out,
                       float* __restrict__ ent_acc) {
    const int n = blockIdx.x * blockDim.x + threadIdx.x;
    const float* xr = x + n * 64;
    float xv[64];
#pragma unroll
    for (int c4 = 0; c4 < 16; c4++) {
        float4 v = *(const float4*)(xr + 4 * c4);
        xv[4 * c4 + 0] = v.x; xv[4 * c4 + 1] = v.y;
        xv[4 * c4 + 2] = v.z; xv[4 * c4 + 3] = v.w;
    }
    float logit[32];
#pragma unroll
    for (int k = 0; k < 32; k++) logit[k] = b2[k];
#pragma unroll 2
    for (int j = 0; j < 64; j++) {
        const float* w1r = w1t + j * 64;   // uniform address -> scalar loads
        float p0 = b1[j], p1 = 0.f, p2 = 0.f, p3 = 0.f;
#pragma unroll
        for (int c = 0; c < 64; c += 4) {
            p0 = fmaf(xv[c + 0], w1r[c + 0], p0);
            p1 = fmaf(xv[c + 1], w1r[c + 1], p1);
            p2 = fmaf(xv[c + 2], w1r[c + 2], p2);
            p3 = fmaf(xv[c + 3], w1r[c + 3], p3);
        }
        float hj = fmaxf((p0 + p1) + (p2 + p3), 0.f);
        const float* w2r = W2 + j * 32;    // uniform -> scalar loads
#pragma unroll
        for (int k = 0; k < 32; k++) logit[k] = fmaf(hj, w2r[k], logit[k]);
    }
    const float sc = scaling[0];
    const float* ur = u + n * 32;
    float m = -3.0e38f;
#pragma unroll
    for (int k4 = 0; k4 < 8; k4++) {
        float4 uv = *(const float4*)(ur + 4 * k4);
        float us[4] = {uv.x, uv.y, uv.z, uv.w};
#pragma unroll
        for (int q = 0; q < 4; q++) {
            const int k = 4 * k4 + q;
            float l = logit[k] * sc;
            l = (amask[k] == 0.f) ? -1e9f : l;
            float g = -__logf(-__logf(us[q] + EPS) + EPS);
            float z = l + g;                // TAU = 1
            logit[k] = z;
            m = fmaxf(m, z);
        }
    }
    float e0 = 0.f, e1 = 0.f, e2 = 0.f, e3 = 0.f;
#pragma unroll
    for (int k = 0; k < 32; k += 4) {
        float a = __expf(logit[k] - m);     logit[k] = a;     e0 += a;
        float b = __expf(logit[k + 1] - m); logit[k + 1] = b; e1 += b;
        float c = __expf(logit[k + 2] - m); logit[k + 2] = c; e2 += c;
        float d = __expf(logit[k + 3] - m); logit[k + 3] = d; e3 += d;
    }
    const float inv = 1.f / ((e0 + e1) + (e2 + e3));
    float ent = 0.f;
#pragma unroll
    for (int k = 0; k < 32; k++) {
        float sv = logit[k] * inv;
        logit[k] = sv;
        ent += sv * __logf(sv + EPS);
    }
    float* so = s_out + n * 32;
#pragma unroll
    for (int k4 = 0; k4 < 8; k4++)
        *(float4*)(so + 4 * k4) = make_float4(logit[4 * k4], logit[4 * k4 + 1],
                                              logit[4 * k4 + 2], logit[4 * k4 + 3]);
    // wave-level reduce then one atomic per wave
#pragma unroll
    for (int off = 32; off > 0; off >>= 1) ent += __shfl_down(ent, off, 64);
    if ((threadIdx.x & 63) == 0) atomicAdd(ent_acc, ent);
}

// pooled outer product: bacc[b][k][f] += s[n,k] * feat[n,f]
// thread = (sub 0..7, k 0..31); block handles 128 contiguous nodes
__global__ void pool_k(const float* __restrict__ s,
                       const float* __restrict__ x,
                       const float* __restrict__ pos,
                       const int* __restrict__ batch,
                       float* __restrict__ bacc) {
    const int t = threadIdx.x;
    const int k = t & 31;
    const int sub = t >> 5;
    const int base = blockIdx.x * 128;
    float acc[68];
#pragma unroll
    for (int f = 0; f < 68; f++) acc[f] = 0.f;
    int cur_b = batch[base + sub];
    for (int i = 0; i < 16; i++) {
        const int n = base + i * 8 + sub;
        const int b = batch[n];
        if (b != cur_b) {                   // rare (batch sorted): per-lane flush
            float* dst = bacc + (cur_b * 32 + k) * FP;
#pragma unroll
            for (int f = 0; f < 68; f++) { atomicAdd(dst + f, acc[f]); acc[f] = 0.f; }
            cur_b = b;
        }
        const float sv = s[n * 32 + k];     // fully coalesced across wave
        const float* xr = x + n * 64;
#pragma unroll
        for (int c4 = 0; c4 < 16; c4++) {
            float4 v = *(const float4*)(xr + 4 * c4);
            acc[4 * c4 + 0] = fmaf(sv, v.x, acc[4 * c4 + 0]);
            acc[4 * c4 + 1] = fmaf(sv, v.y, acc[4 * c4 + 1]);
            acc[4 * c4 + 2] = fmaf(sv, v.z, acc[4 * c4 + 2]);
            acc[4 * c4 + 3] = fmaf(sv, v.w, acc[4 * c4 + 3]);
        }
        float2 p = *(const float2*)(pos + n * 2);
        acc[64] = fmaf(sv, p.x, acc[64]);
        acc[65] = fmaf(sv, p.y, acc[65]);
        acc[66] = fmaf(sv, p.x * p.x + p.y * p.y, acc[66]);
        acc[67] += sv;
    }
    __shared__ int b0;
    __shared__ float red[32][69];
    if (t == 0) b0 = cur_b;
    for (int idx = t; idx < 32 * 69; idx += 256) ((float*)red)[idx] = 0.f;
    __syncthreads();
    const bool uni = (__syncthreads_and(cur_b == b0) != 0);
    if (uni) {                              // common case: reduce 8 subs in LDS, 2176 atomics/block
#pragma unroll
        for (int f = 0; f < 68; f++) atomicAdd(&red[k][f], acc[f]);
        __syncthreads();
        const int k2 = t >> 3;
        for (int f = (t & 7); f < 68; f += 8)
            atomicAdd(bacc + (b0 * 32 + k2) * FP + f, red[k2][f]);
    } else {                                // boundary block: per-lane flush
        float* dst = bacc + (cur_b * 32 + k) * FP;
#pragma unroll
        for (int f = 0; f < 68; f++) atomicAdd(dst + f, acc[f]);
    }
}

// single block: out copy, mu, all six scalars
__global__ void fin_k(const float* __restrict__ ws,
                      const float* __restrict__ amask,
                      float* __restrict__ outp) {
    const int t = threadIdx.x;
    const float* bacc = ws + WS_BACC;
    for (int idx = t; idx < BB * KK * CD; idx += 256) {
        int bk = idx >> 6, c = idx & 63;
        outp[OUT_OUT + idx] = bacc[bk * FP + c];
    }
    __shared__ float mu_s[BB * KK * 2];
    for (int idx = t; idx < BB * KK * 2; idx += 256) {
        int bk = idx >> 1, d = idx & 1;
        float v = bacc[bk * FP + 64 + d] / (bacc[bk * FP + 67] + EPS);
        mu_s[idx] = v;
        outp[OUT_MU + idx] = v;
    }
    __shared__ float kred[32][4];
    if (t < 32) {
        float S = 0, px = 0, py = 0, sq = 0;
        for (int b = 0; b < 16; b++) {
            const float* pp = bacc + (b * 32 + t) * FP;
            S += pp[67]; px += pp[64]; py += pp[65]; sq += pp[66];
        }
        float avg = S / (float)NN;
        float am = amask[t];
        float ssum = S + EPS;
        float mx = px / ssum, my = py / ssum;
        kred[t][0] = avg * __logf(avg + EPS);          // diversity term
        kred[t][1] = fabsf(avg * (1.f - am));          // pruning term
        kred[t][2] = sq / ssum - mx * mx - my * my;    // spatial var
        kred[t][3] = am;                               // sparsity term
    }
    __syncthreads();
    float sep = 0.f;
    for (int idx = t; idx < BB * KK * KK; idx += 256) {
        int b = idx >> 10, i = (idx >> 5) & 31, j = idx & 31;
        if (i != j) {
            float dx = mu_s[(b * 32 + i) * 2 + 0] - mu_s[(b * 32 + j) * 2 + 0];
            float dy = mu_s[(b * 32 + i) * 2 + 1] - mu_s[(b * 32 + j) * 2 + 1];
            sep += 1.f / (dx * dx + dy * dy + 1.f);
        }
    }
    __shared__ float red[256];
    red[t] = sep;
    __syncthreads();
    for (int s2 = 128; s2 > 0; s2 >>= 1) {
        if (t < s2) red[t] += red[t + s2];
        __syncthreads();
    }
    if (t == 0) {
        float div = 0, pru = 0, spa = 0, spar = 0;
        for (int kq = 0; kq < 32; kq++) {
            div += kred[kq][0]; pru += kred[kq][1];
            spa += kred[kq][2]; spar += kred[kq][3];
        }
        outp[OUT_SCAL + 0] = -ws[WS_ENT] / (float)NN;        // entropy
        outp[OUT_SCAL + 1] = div;                            // diversity
        outp[OUT_SCAL + 2] = spa / 32.f;                     // spatial
        outp[OUT_SCAL + 3] = pru / 32.f;                     // pruning
        outp[OUT_SCAL + 4] = spar / 32.f;                    // sparsity
        outp[OUT_SCAL + 5] = red[0] / (32.f * 31.f + EPS);   // separation
    }
}

extern "C" void kernel_launch(void* const* d_in, const int* in_sizes, int n_in,
                              void* d_out, int out_size, void* d_ws, size_t ws_size,
                              hipStream_t stream) {
    const float* x       = (const float*)d_in[0];
    const int*   batch   = (const int*)d_in[1];
    const float* pos     = (const float*)d_in[2];
    const float* u       = (const float*)d_in[3];
    const float* W1      = (const float*)d_in[4];
    const float* b1      = (const float*)d_in[5];
    const float* W2      = (const float*)d_in[6];
    const float* b2      = (const float*)d_in[7];
    const float* scaling = (const float*)d_in[8];
    const float* amask   = (const float*)d_in[9];
    float* outp = (float*)d_out;
    float* ws   = (float*)d_ws;

    hipMemsetAsync(ws, 0, (size_t)(WS_BACC + WS_BACC_SZ) * sizeof(float), stream);
    prep_k<<<16, 256, 0, stream>>>(W1, ws);
    node_k<<<NN / 256, 256, 0, stream>>>(x, u, ws + WS_W1T, b1, W2, b2, scaling, amask,
                                         outp + OUT_S, ws + WS_ENT);
    pool_k<<<NN / 128, 256, 0, stream>>>(outp + OUT_S, x, pos, batch, ws + WS_BACC);
    fin_k<<<1, 256, 0, stream>>>(ws, amask, outp);
}

// Round 2
// 342.289 us; speedup vs baseline: 1.1650x; 1.1650x over previous
//
#include <hip/hip_runtime.h>

#define EPS 1e-9f
constexpr int NN = 131072;
constexpr int CD = 64;
constexpr int KK = 32;
constexpr int BB = 16;

// ---- workspace layout (float offsets) ----
constexpr int WS_ENT  = 0;                    // entropy accumulator (1 float)
constexpr int WS_BACC = 16;                   // bacc[B][K][FP]: f 0..63 = x, 64 px, 65 py, 66 |p|^2, 67 = 1
constexpr int FP      = 72;                   // padded feature count
constexpr int WS_BACC_SZ = BB * KK * FP;      // 36864
constexpr int WS_W1T  = WS_BACC + WS_BACC_SZ; // transposed W1 [j][c]

// ---- output layout (float offsets), tuple order of the reference ----
constexpr int OUT_OUT  = 0;                   // [B,K,C] = 32768
constexpr int OUT_S    = BB * KK * CD;        // s [N,K]
constexpr int OUT_SCAL = OUT_S + NN * KK;     // entropy, diversity, spatial, pruning, sparsity, separation
constexpr int OUT_MU   = OUT_SCAL + 6;        // mu [B,K,2]

// one-time transpose of W1 so columns are contiguous (enables s_load rows)
__global__ void prep_k(const float* __restrict__ W1, float* __restrict__ ws) {
    int t = blockIdx.x * 256 + threadIdx.x;   // 4096 threads
    int c = t >> 6, j = t & 63;
    ws[WS_W1T + j * 64 + c] = W1[c * 64 + j];
}

// per-node: MLP -> scale/mask -> gumbel -> softmax -> s ; entropy partial
__global__ void node_k(const float* __restrict__ x,
                       const float* __restrict__ u,
                       const float* __restrict__ w1t,
                       const float* __restrict__ b1,
                       const float* __restrict__ W2,
                       const float* __restrict__ b2,
                       const float* __restrict__ scaling,
                       const float* __restrict__ amask,
                       float* __restrict__ s_out,
                       float* __restrict__ ent_acc) {
    const int n = blockIdx.x * blockDim.x + threadIdx.x;
    const float* xr = x + n * 64;
    float xv[64];
#pragma unroll
    for (int c4 = 0; c4 < 16; c4++) {
        float4 v = *(const float4*)(xr + 4 * c4);
        xv[4 * c4 + 0] = v.x; xv[4 * c4 + 1] = v.y;
        xv[4 * c4 + 2] = v.z; xv[4 * c4 + 3] = v.w;
    }
    float logit[32];
#pragma unroll
    for (int k = 0; k < 32; k++) logit[k] = b2[k];
#pragma unroll 2
    for (int j = 0; j < 64; j++) {
        const float* w1r = w1t + j * 64;   // uniform address -> scalar loads
        float p0 = b1[j], p1 = 0.f, p2 = 0.f, p3 = 0.f;
#pragma unroll
        for (int c = 0; c < 64; c += 4) {
            p0 = fmaf(xv[c + 0], w1r[c + 0], p0);
            p1 = fmaf(xv[c + 1], w1r[c + 1], p1);
            p2 = fmaf(xv[c + 2], w1r[c + 2], p2);
            p3 = fmaf(xv[c + 3], w1r[c + 3], p3);
        }
        float hj = fmaxf((p0 + p1) + (p2 + p3), 0.f);
        const float* w2r = W2 + j * 32;    // uniform -> scalar loads
#pragma unroll
        for (int k = 0; k < 32; k++) logit[k] = fmaf(hj, w2r[k], logit[k]);
    }
    const float sc = scaling[0];
    const float* ur = u + n * 32;
    float m = -3.0e38f;
#pragma unroll
    for (int k4 = 0; k4 < 8; k4++) {
        float4 uv = *(const float4*)(ur + 4 * k4);
        float us[4] = {uv.x, uv.y, uv.z, uv.w};
#pragma unroll
        for (int q = 0; q < 4; q++) {
            const int k = 4 * k4 + q;
            float l = logit[k] * sc;
            l = (amask[k] == 0.f) ? -1e9f : l;
            float g = -__logf(-__logf(us[q] + EPS) + EPS);
            float z = l + g;                // TAU = 1
            logit[k] = z;
            m = fmaxf(m, z);
        }
    }
    float e0 = 0.f, e1 = 0.f, e2 = 0.f, e3 = 0.f;
#pragma unroll
    for (int k = 0; k < 32; k += 4) {
        float a = __expf(logit[k] - m);     logit[k] = a;     e0 += a;
        float b = __expf(logit[k + 1] - m); logit[k + 1] = b; e1 += b;
        float c = __expf(logit[k + 2] - m); logit[k + 2] = c; e2 += c;
        float d = __expf(logit[k + 3] - m); logit[k + 3] = d; e3 += d;
    }
    const float inv = 1.f / ((e0 + e1) + (e2 + e3));
    float ent = 0.f;
#pragma unroll
    for (int k = 0; k < 32; k++) {
        float sv = logit[k] * inv;
        logit[k] = sv;
        ent += sv * __logf(sv + EPS);
    }
    float* so = s_out + n * 32;
#pragma unroll
    for (int k4 = 0; k4 < 8; k4++)
        *(float4*)(so + 4 * k4) = make_float4(logit[4 * k4], logit[4 * k4 + 1],
                                              logit[4 * k4 + 2], logit[4 * k4 + 3]);
    // wave-level reduce then one atomic per wave
#pragma unroll
    for (int off = 32; off > 0; off >>= 1) ent += __shfl_down(ent, off, 64);
    if ((threadIdx.x & 63) == 0) atomicAdd(ent_acc, ent);
}

// pooled outer product, feature-split: thread (k, fg) owns features fg*8..fg*8+7
// (+ one extra feature for fg<4). All threads walk the same node n in lockstep:
// batch[n] is block-uniform (scalar load, uniform flush branch), s coalesced.
constexpr int NPB = 128;  // nodes per block
__global__ void pool_k(const float* __restrict__ s,
                       const float* __restrict__ x,
                       const float* __restrict__ pos,
                       const int* __restrict__ batch,
                       float* __restrict__ bacc) {
    const int t = threadIdx.x;
    const int k = t & 31;
    const int fg = t >> 5;              // 0..7
    const int base = blockIdx.x * NPB;
    float acc[8];
    float accx = 0.f;                   // fg==0: px, 1: py, 2: |p|^2, 3: sum
#pragma unroll
    for (int f = 0; f < 8; f++) acc[f] = 0.f;
    int cur_b = batch[base];
#pragma unroll 2
    for (int n = base; n < base + NPB; n++) {
        const int b = batch[n];         // block-uniform
        if (b != cur_b) {               // uniform, rare (batch sorted)
            float* dst = bacc + (cur_b * 32 + k) * FP;
#pragma unroll
            for (int f = 0; f < 8; f++) { atomicAdd(dst + fg * 8 + f, acc[f]); acc[f] = 0.f; }
            if (fg < 4) { atomicAdd(dst + 64 + fg, accx); accx = 0.f; }
            cur_b = b;
        }
        const float sv = s[n * 32 + k]; // coalesced across the wave
        const float4 v0 = *(const float4*)(x + n * 64 + fg * 8);      // broadcast per fg
        const float4 v1 = *(const float4*)(x + n * 64 + fg * 8 + 4);
        acc[0] = fmaf(sv, v0.x, acc[0]);
        acc[1] = fmaf(sv, v0.y, acc[1]);
        acc[2] = fmaf(sv, v0.z, acc[2]);
        acc[3] = fmaf(sv, v0.w, acc[3]);
        acc[4] = fmaf(sv, v1.x, acc[4]);
        acc[5] = fmaf(sv, v1.y, acc[5]);
        acc[6] = fmaf(sv, v1.z, acc[6]);
        acc[7] = fmaf(sv, v1.w, acc[7]);
        if (fg < 4) {                   // wave-uniform branch (fg pairs per wave)
            float2 p = *(const float2*)(pos + n * 2);                 // broadcast
            float e = (fg == 0) ? p.x : (fg == 1) ? p.y
                    : (fg == 2) ? (p.x * p.x + p.y * p.y) : 1.f;
            accx = fmaf(sv, e, accx);
        }
    }
    float* dst = bacc + (cur_b * 32 + k) * FP;
#pragma unroll
    for (int f = 0; f < 8; f++) atomicAdd(dst + fg * 8 + f, acc[f]);
    if (fg < 4) atomicAdd(dst + 64 + fg, accx);
}

// many-block copy of pooled features to d_out (was latency-serial in 1-block fin_k)
__global__ void copy_k(const float* __restrict__ ws, float* __restrict__ outp) {
    const float* bacc = ws + WS_BACC;
    int idx = blockIdx.x * 256 + threadIdx.x;   // 32768 threads
    int bk = idx >> 6, c = idx & 63;
    outp[OUT_OUT + idx] = bacc[bk * FP + c];
}

// single block: mu + all six scalars (small now)
__global__ void fin_k(const float* __restrict__ ws,
                      const float* __restrict__ amask,
                      float* __restrict__ outp) {
    const int t = threadIdx.x;
    const float* bacc = ws + WS_BACC;
    __shared__ float mu_s[BB * KK * 2];
    for (int idx = t; idx < BB * KK * 2; idx += 256) {
        int bk = idx >> 1, d = idx & 1;
        float v = bacc[bk * FP + 64 + d] / (bacc[bk * FP + 67] + EPS);
        mu_s[idx] = v;
        outp[OUT_MU + idx] = v;
    }
    __shared__ float kred[32][4];
    if (t < 32) {
        float S = 0, px = 0, py = 0, sq = 0;
        for (int b = 0; b < 16; b++) {
            const float* pp = bacc + (b * 32 + t) * FP;
            S += pp[67]; px += pp[64]; py += pp[65]; sq += pp[66];
        }
        float avg = S / (float)NN;
        float am = amask[t];
        float ssum = S + EPS;
        float mx = px / ssum, my = py / ssum;
        kred[t][0] = avg * __logf(avg + EPS);          // diversity term
        kred[t][1] = fabsf(avg * (1.f - am));          // pruning term
        kred[t][2] = sq / ssum - mx * mx - my * my;    // spatial var
        kred[t][3] = am;                               // sparsity term
    }
    __syncthreads();
    float sep = 0.f;
    for (int idx = t; idx < BB * KK * KK; idx += 256) {
        int b = idx >> 10, i = (idx >> 5) & 31, j = idx & 31;
        if (i != j) {
            float dx = mu_s[(b * 32 + i) * 2 + 0] - mu_s[(b * 32 + j) * 2 + 0];
            float dy = mu_s[(b * 32 + i) * 2 + 1] - mu_s[(b * 32 + j) * 2 + 1];
            sep += 1.f / (dx * dx + dy * dy + 1.f);
        }
    }
    __shared__ float red[256];
    red[t] = sep;
    __syncthreads();
    for (int s2 = 128; s2 > 0; s2 >>= 1) {
        if (t < s2) red[t] += red[t + s2];
        __syncthreads();
    }
    if (t == 0) {
        float div = 0, pru = 0, spa = 0, spar = 0;
        for (int kq = 0; kq < 32; kq++) {
            div += kred[kq][0]; pru += kred[kq][1];
            spa += kred[kq][2]; spar += kred[kq][3];
        }
        outp[OUT_SCAL + 0] = -ws[WS_ENT] / (float)NN;        // entropy
        outp[OUT_SCAL + 1] = div;                            // diversity
        outp[OUT_SCAL + 2] = spa / 32.f;                     // spatial
        outp[OUT_SCAL + 3] = pru / 32.f;                     // pruning
        outp[OUT_SCAL + 4] = spar / 32.f;                    // sparsity
        outp[OUT_SCAL + 5] = red[0] / (32.f * 31.f + EPS);   // separation
    }
}

extern "C" void kernel_launch(void* const* d_in, const int* in_sizes, int n_in,
                              void* d_out, int out_size, void* d_ws, size_t ws_size,
                              hipStream_t stream) {
    const float* x       = (const float*)d_in[0];
    const int*   batch   = (const int*)d_in[1];
    const float* pos     = (const float*)d_in[2];
    const float* u       = (const float*)d_in[3];
    const float* W1      = (const float*)d_in[4];
    const float* b1      = (const float*)d_in[5];
    const float* W2      = (const float*)d_in[6];
    const float* b2      = (const float*)d_in[7];
    const float* scaling = (const float*)d_in[8];
    const float* amask   = (const float*)d_in[9];
    float* outp = (float*)d_out;
    float* ws   = (float*)d_ws;

    hipMemsetAsync(ws, 0, (size_t)(WS_BACC + WS_BACC_SZ) * sizeof(float), stream);
    prep_k<<<16, 256, 0, stream>>>(W1, ws);
    node_k<<<NN / 256, 256, 0, stream>>>(x, u, ws + WS_W1T, b1, W2, b2, scaling, amask,
                                         outp + OUT_S, ws + WS_ENT);
    pool_k<<<NN / NPB, 256, 0, stream>>>(outp + OUT_S, x, pos, batch, ws + WS_BACC);
    copy_k<<<BB * KK * CD / 256, 256, 0, stream>>>(ws, outp);
    fin_k<<<1, 256, 0, stream>>>(ws, amask, outp);
}

// Round 3
// 316.502 us; speedup vs baseline: 1.2599x; 1.0815x over previous
//
#include <hip/hip_runtime.h>

#define EPS 1e-9f
constexpr int NN = 131072;
constexpr int CD = 64;
constexpr int KK = 32;
constexpr int BB = 16;

// ---- workspace layout (float offsets) ----
constexpr int WS_ENT  = 0;                    // entropy accumulator (1 float)
constexpr int WS_BACC = 16;                   // bacc[B][K][FP]: f 0..63 = x, 64 px, 65 py, 66 |p|^2, 67 = 1
constexpr int FP      = 72;                   // padded feature count
constexpr int WS_BACC_SZ = BB * KK * FP;      // 36864
constexpr int WS_W1T  = WS_BACC + WS_BACC_SZ; // transposed W1 [j][c], 4096
constexpr int WS_TAG  = WS_W1T + 4096;        // int tag per pool block (<=1024)
constexpr int WS_PART = WS_TAG + 1040;        // per-block partials [nblk][68*32]
constexpr int CELLS   = 68 * 32;              // 2176 cells per partial tile

// ---- output layout (float offsets), tuple order of the reference ----
constexpr int OUT_OUT  = 0;                   // [B,K,C] = 32768
constexpr int OUT_S    = BB * KK * CD;        // s [N,K]
constexpr int OUT_SCAL = OUT_S + NN * KK;     // entropy, diversity, spatial, pruning, sparsity, separation
constexpr int OUT_MU   = OUT_SCAL + 6;        // mu [B,K,2]

// one-time transpose of W1 so columns are contiguous (enables s_load rows)
__global__ void prep_k(const float* __restrict__ W1, float* __restrict__ ws) {
    int t = blockIdx.x * 256 + threadIdx.x;   // 4096 threads
    int c = t >> 6, j = t & 63;
    ws[WS_W1T + j * 64 + c] = W1[c * 64 + j];
}

// per-node: MLP -> scale/mask -> gumbel -> softmax -> s ; entropy partial
__global__ void node_k(const float* __restrict__ x,
                       const float* __restrict__ u,
                       const float* __restrict__ w1t,
                       const float* __restrict__ b1,
                       const float* __restrict__ W2,
                       const float* __restrict__ b2,
                       const float* __restrict__ scaling,
                       const float* __restrict__ amask,
                       float* __restrict__ s_out,
                       float* __restrict__ ent_acc) {
    const int n = blockIdx.x * blockDim.x + threadIdx.x;
    const float* xr = x + n * 64;
    float xv[64];
#pragma unroll
    for (int c4 = 0; c4 < 16; c4++) {
        float4 v = *(const float4*)(xr + 4 * c4);
        xv[4 * c4 + 0] = v.x; xv[4 * c4 + 1] = v.y;
        xv[4 * c4 + 2] = v.z; xv[4 * c4 + 3] = v.w;
    }
    float logit[32];
#pragma unroll
    for (int k = 0; k < 32; k++) logit[k] = b2[k];
#pragma unroll 2
    for (int j = 0; j < 64; j++) {
        const float* w1r = w1t + j * 64;   // uniform address -> scalar loads
        float p0 = b1[j], p1 = 0.f, p2 = 0.f, p3 = 0.f;
#pragma unroll
        for (int c = 0; c < 64; c += 4) {
            p0 = fmaf(xv[c + 0], w1r[c + 0], p0);
            p1 = fmaf(xv[c + 1], w1r[c + 1], p1);
            p2 = fmaf(xv[c + 2], w1r[c + 2], p2);
            p3 = fmaf(xv[c + 3], w1r[c + 3], p3);
        }
        float hj = fmaxf((p0 + p1) + (p2 + p3), 0.f);
        const float* w2r = W2 + j * 32;    // uniform -> scalar loads
#pragma unroll
        for (int k = 0; k < 32; k++) logit[k] = fmaf(hj, w2r[k], logit[k]);
    }
    const float sc = scaling[0];
    const float* ur = u + n * 32;
    float m = -3.0e38f;
#pragma unroll
    for (int k4 = 0; k4 < 8; k4++) {
        float4 uv = *(const float4*)(ur + 4 * k4);
        float us[4] = {uv.x, uv.y, uv.z, uv.w};
#pragma unroll
        for (int q = 0; q < 4; q++) {
            const int k = 4 * k4 + q;
            float l = logit[k] * sc;
            l = (amask[k] == 0.f) ? -1e9f : l;
            float g = -__logf(-__logf(us[q] + EPS) + EPS);
            float z = l + g;                // TAU = 1
            logit[k] = z;
            m = fmaxf(m, z);
        }
    }
    float e0 = 0.f, e1 = 0.f, e2 = 0.f, e3 = 0.f;
#pragma unroll
    for (int k = 0; k < 32; k += 4) {
        float a = __expf(logit[k] - m);     logit[k] = a;     e0 += a;
        float b = __expf(logit[k + 1] - m); logit[k + 1] = b; e1 += b;
        float c = __expf(logit[k + 2] - m); logit[k + 2] = c; e2 += c;
        float d = __expf(logit[k + 3] - m); logit[k + 3] = d; e3 += d;
    }
    const float inv = 1.f / ((e0 + e1) + (e2 + e3));
    float ent = 0.f;
#pragma unroll
    for (int k = 0; k < 32; k++) {
        float sv = logit[k] * inv;
        logit[k] = sv;
        ent += sv * __logf(sv + EPS);
    }
    float* so = s_out + n * 32;
#pragma unroll
    for (int k4 = 0; k4 < 8; k4++)
        *(float4*)(so + 4 * k4) = make_float4(logit[4 * k4], logit[4 * k4 + 1],
                                              logit[4 * k4 + 2], logit[4 * k4 + 3]);
    // wave-level reduce then one atomic per wave
#pragma unroll
    for (int off = 32; off > 0; off >>= 1) ent += __shfl_down(ent, off, 64);
    if ((threadIdx.x & 63) == 0) atomicAdd(ent_acc, ent);
}

// pooled outer product, feature-split: thread (k, fg) owns features fg*8..fg*8+7
// (+ one extra for fg<4). Per-block partial tile -> plain stores (NO atomics in
// the common path); only mid-block batch boundaries flush via atomics (rare).
__global__ void pool_k(const float* __restrict__ s,
                       const float* __restrict__ x,
                       const float* __restrict__ pos,
                       const int* __restrict__ batch,
                       float* __restrict__ bacc,
                       float* __restrict__ part,
                       int* __restrict__ tags,
                       int npb) {
    const int t = threadIdx.x;
    const int k = t & 31;
    const int fg = t >> 5;              // 0..7
    const int base = blockIdx.x * npb;
    float acc[8];
    float accx = 0.f;                   // fg==0: px, 1: py, 2: |p|^2, 3: sum
#pragma unroll
    for (int f = 0; f < 8; f++) acc[f] = 0.f;
    int cur_b = batch[base];
#pragma unroll 2
    for (int n = base; n < base + npb; n++) {
        const int b = batch[n];         // block-uniform scalar load
        if (b != cur_b) {               // uniform, rare (batch sorted, ~15 blocks total)
            float* dst = bacc + (cur_b * 32 + k) * FP;
#pragma unroll
            for (int f = 0; f < 8; f++) { atomicAdd(dst + fg * 8 + f, acc[f]); acc[f] = 0.f; }
            if (fg < 4) { atomicAdd(dst + 64 + fg, accx); accx = 0.f; }
            cur_b = b;
        }
        const float sv = s[n * 32 + k]; // coalesced across the wave
        const float4 v0 = *(const float4*)(x + n * 64 + fg * 8);      // broadcast per fg
        const float4 v1 = *(const float4*)(x + n * 64 + fg * 8 + 4);
        acc[0] = fmaf(sv, v0.x, acc[0]);
        acc[1] = fmaf(sv, v0.y, acc[1]);
        acc[2] = fmaf(sv, v0.z, acc[2]);
        acc[3] = fmaf(sv, v0.w, acc[3]);
        acc[4] = fmaf(sv, v1.x, acc[4]);
        acc[5] = fmaf(sv, v1.y, acc[5]);
        acc[6] = fmaf(sv, v1.z, acc[6]);
        acc[7] = fmaf(sv, v1.w, acc[7]);
        if (fg < 4) {                   // wave-uniform branch
            float2 p = *(const float2*)(pos + n * 2);                 // broadcast
            float e = (fg == 0) ? p.x : (fg == 1) ? p.y
                    : (fg == 2) ? (p.x * p.x + p.y * p.y) : 1.f;
            accx = fmaf(sv, e, accx);
        }
    }
    // plain coalesced partial store: layout part[blk][f*32 + k]
    float* pp = part + (size_t)blockIdx.x * CELLS;
#pragma unroll
    for (int f = 0; f < 8; f++) pp[(fg * 8 + f) * 32 + k] = acc[f];
    if (fg < 4) pp[(64 + fg) * 32 + k] = accx;
    if (t == 0) tags[blockIdx.x] = cur_b;
}

// one thread per (b,k,f) cell: sum matching-tag partials (block-uniform scan),
// add boundary-atomic residue already in bacc, write bacc AND out directly.
__global__ void reduce_k(const float* __restrict__ part,
                         const int* __restrict__ tags,
                         float* __restrict__ bacc,
                         float* __restrict__ outp,
                         int nblk) {
    const int b = blockIdx.x;                   // 0..15
    const int cell = blockIdx.y * 256 + threadIdx.x;
    if (cell >= CELLS) return;
    const int k = cell & 31, f = cell >> 5;
    float v = 0.f;
    for (int blk = 0; blk < nblk; blk++) {
        if (tags[blk] == b)                     // block-uniform compare
            v += part[(size_t)blk * CELLS + cell];
    }
    const int idx = (b * 32 + k) * FP + f;
    const float tot = bacc[idx] + v;            // + boundary flushes
    bacc[idx] = tot;
    if (f < 64) outp[OUT_OUT + ((b * 32 + k) << 6) + f] = tot;
}

// single block: mu + all six scalars
__global__ void fin_k(const float* __restrict__ ws,
                      const float* __restrict__ amask,
                      float* __restrict__ outp) {
    const int t = threadIdx.x;
    const float* bacc = ws + WS_BACC;
    __shared__ float mu_s[BB * KK * 2];
    for (int idx = t; idx < BB * KK * 2; idx += 256) {
        int bk = idx >> 1, d = idx & 1;
        float v = bacc[bk * FP + 64 + d] / (bacc[bk * FP + 67] + EPS);
        mu_s[idx] = v;
        outp[OUT_MU + idx] = v;
    }
    __shared__ float kred[32][4];
    if (t < 32) {
        float S = 0, px = 0, py = 0, sq = 0;
        for (int b = 0; b < 16; b++) {
            const float* pp = bacc + (b * 32 + t) * FP;
            S += pp[67]; px += pp[64]; py += pp[65]; sq += pp[66];
        }
        float avg = S / (float)NN;
        float am = amask[t];
        float ssum = S + EPS;
        float mx = px / ssum, my = py / ssum;
        kred[t][0] = avg * __logf(avg + EPS);          // diversity term
        kred[t][1] = fabsf(avg * (1.f - am));          // pruning term
        kred[t][2] = sq / ssum - mx * mx - my * my;    // spatial var
        kred[t][3] = am;                               // sparsity term
    }
    __syncthreads();
    float sep = 0.f;
    for (int idx = t; idx < BB * KK * KK; idx += 256) {
        int b = idx >> 10, i = (idx >> 5) & 31, j = idx & 31;
        if (i != j) {
            float dx = mu_s[(b * 32 + i) * 2 + 0] - mu_s[(b * 32 + j) * 2 + 0];
            float dy = mu_s[(b * 32 + i) * 2 + 1] - mu_s[(b * 32 + j) * 2 + 1];
            sep += 1.f / (dx * dx + dy * dy + 1.f);
        }
    }
    __shared__ float red[256];
    red[t] = sep;
    __syncthreads();
    for (int s2 = 128; s2 > 0; s2 >>= 1) {
        if (t < s2) red[t] += red[t + s2];
        __syncthreads();
    }
    if (t == 0) {
        float div = 0, pru = 0, spa = 0, spar = 0;
        for (int kq = 0; kq < 32; kq++) {
            div += kred[kq][0]; pru += kred[kq][1];
            spa += kred[kq][2]; spar += kred[kq][3];
        }
        outp[OUT_SCAL + 0] = -ws[WS_ENT] / (float)NN;        // entropy
        outp[OUT_SCAL + 1] = div;                            // diversity
        outp[OUT_SCAL + 2] = spa / 32.f;                     // spatial
        outp[OUT_SCAL + 3] = pru / 32.f;                     // pruning
        outp[OUT_SCAL + 4] = spar / 32.f;                    // sparsity
        outp[OUT_SCAL + 5] = red[0] / (32.f * 31.f + EPS);   // separation
    }
}

extern "C" void kernel_launch(void* const* d_in, const int* in_sizes, int n_in,
                              void* d_out, int out_size, void* d_ws, size_t ws_size,
                              hipStream_t stream) {
    const float* x       = (const float*)d_in[0];
    const int*   batch   = (const int*)d_in[1];
    const float* pos     = (const float*)d_in[2];
    const float* u       = (const float*)d_in[3];
    const float* W1      = (const float*)d_in[4];
    const float* b1      = (const float*)d_in[5];
    const float* W2      = (const float*)d_in[6];
    const float* b2      = (const float*)d_in[7];
    const float* scaling = (const float*)d_in[8];
    const float* amask   = (const float*)d_in[9];
    float* outp = (float*)d_out;
    float* ws   = (float*)d_ws;

    // choose nodes-per-block so the partial buffer fits ws (prefers 1024 blocks)
    int npb = 128;
    while (npb < NN &&
           ws_size < ((size_t)WS_PART + (size_t)(NN / npb) * CELLS) * sizeof(float))
        npb <<= 1;
    const int nblk = NN / npb;

    hipMemsetAsync(ws, 0, (size_t)(WS_BACC + WS_BACC_SZ) * sizeof(float), stream);
    prep_k<<<16, 256, 0, stream>>>(W1, ws);
    node_k<<<NN / 256, 256, 0, stream>>>(x, u, ws + WS_W1T, b1, W2, b2, scaling, amask,
                                         outp + OUT_S, ws + WS_ENT);
    pool_k<<<nblk, 256, 0, stream>>>(outp + OUT_S, x, pos, batch,
                                     ws + WS_BACC, ws + WS_PART, (int*)(ws + WS_TAG), npb);
    reduce_k<<<dim3(BB, (CELLS + 255) / 256), 256, 0, stream>>>(
        ws + WS_PART, (const int*)(ws + WS_TAG), ws + WS_BACC, outp, nblk);
    fin_k<<<1, 256, 0, stream>>>(ws, amask, outp);
}

// Round 4
// 264.878 us; speedup vs baseline: 1.5055x; 1.1949x over previous
//
#include <hip/hip_runtime.h>

#define EPS 1e-9f
constexpr int NN = 131072;
constexpr int CD = 64;
constexpr int KK = 32;
constexpr int BB = 16;

// ---- workspace layout (float offsets) ----
constexpr int WS_ENT  = 0;                    // entropy accumulator (1 float)
constexpr int WS_BACC = 16;                   // bacc[B][K][FP]: f 0..63 = x, 64 px, 65 py, 66 |p|^2, 67 = 1
constexpr int FP      = 72;                   // padded feature count
constexpr int WS_BACC_SZ = BB * KK * FP;      // 36864
constexpr int WS_W1T  = WS_BACC + WS_BACC_SZ; // transposed W1 [j][c], 4096
constexpr int WS_TAG  = WS_W1T + 4096;        // int tag per pool block (<=1024)
constexpr int WS_PART = WS_TAG + 1040;        // per-block partials [nblk][68*32]
constexpr int CELLS   = 68 * 32;              // 2176 cells per partial tile

// ---- output layout (float offsets), tuple order of the reference ----
constexpr int OUT_OUT  = 0;                   // [B,K,C] = 32768
constexpr int OUT_S    = BB * KK * CD;        // s [N,K]
constexpr int OUT_SCAL = OUT_S + NN * KK;     // entropy, diversity, spatial, pruning, sparsity, separation
constexpr int OUT_MU   = OUT_SCAL + 6;        // mu [B,K,2]

// one-time transpose of W1 so columns are contiguous (enables s_load rows)
__global__ void prep_k(const float* __restrict__ W1, float* __restrict__ ws) {
    int t = blockIdx.x * 256 + threadIdx.x;   // 4096 threads
    int c = t >> 6, j = t & 63;
    ws[WS_W1T + j * 64 + c] = W1[c * 64 + j];
}

// per-node: MLP -> scale/mask -> gumbel -> softmax -> s ; entropy partial
// __launch_bounds__(256,2): VGPR budget 256 so xv[64]+logit[32] stay in
// registers (default heuristic spilled them to scratch: VGPR_Count was 56).
// Grid is 512 blocks (2/CU) so occupancy is grid-capped at 25% regardless.
__global__ __launch_bounds__(256, 2)
void node_k(const float* __restrict__ x,
            const float* __restrict__ u,
            const float* __restrict__ w1t,
            const float* __restrict__ b1,
            const float* __restrict__ W2,
            const float* __restrict__ b2,
            const float* __restrict__ scaling,
            const float* __restrict__ amask,
            float* __restrict__ s_out,
            float* __restrict__ ent_acc) {
    const int n = blockIdx.x * blockDim.x + threadIdx.x;
    const float* xr = x + n * 64;
    float xv[64];
#pragma unroll
    for (int c4 = 0; c4 < 16; c4++) {
        float4 v = *(const float4*)(xr + 4 * c4);
        xv[4 * c4 + 0] = v.x; xv[4 * c4 + 1] = v.y;
        xv[4 * c4 + 2] = v.z; xv[4 * c4 + 3] = v.w;
    }
    float logit[32];
#pragma unroll
    for (int k = 0; k < 32; k++) logit[k] = b2[k];
#pragma unroll 2
    for (int j = 0; j < 64; j++) {
        const float* w1r = w1t + j * 64;   // uniform address -> scalar loads
        float p0 = b1[j], p1 = 0.f, p2 = 0.f, p3 = 0.f;
#pragma unroll
        for (int c = 0; c < 64; c += 4) {
            p0 = fmaf(xv[c + 0], w1r[c + 0], p0);
            p1 = fmaf(xv[c + 1], w1r[c + 1], p1);
            p2 = fmaf(xv[c + 2], w1r[c + 2], p2);
            p3 = fmaf(xv[c + 3], w1r[c + 3], p3);
        }
        float hj = fmaxf((p0 + p1) + (p2 + p3), 0.f);
        const float* w2r = W2 + j * 32;    // uniform -> scalar loads
#pragma unroll
        for (int k = 0; k < 32; k++) logit[k] = fmaf(hj, w2r[k], logit[k]);
    }
    const float sc = scaling[0];
    const float* ur = u + n * 32;
    float m = -3.0e38f;
#pragma unroll
    for (int k4 = 0; k4 < 8; k4++) {
        float4 uv = *(const float4*)(ur + 4 * k4);
        float us[4] = {uv.x, uv.y, uv.z, uv.w};
#pragma unroll
        for (int q = 0; q < 4; q++) {
            const int k = 4 * k4 + q;
            float l = logit[k] * sc;
            l = (amask[k] == 0.f) ? -1e9f : l;
            float g = -__logf(-__logf(us[q] + EPS) + EPS);
            float z = l + g;                // TAU = 1
            logit[k] = z;
            m = fmaxf(m, z);
        }
    }
    float e0 = 0.f, e1 = 0.f, e2 = 0.f, e3 = 0.f;
#pragma unroll
    for (int k = 0; k < 32; k += 4) {
        float a = __expf(logit[k] - m);     logit[k] = a;     e0 += a;
        float b = __expf(logit[k + 1] - m); logit[k + 1] = b; e1 += b;
        float c = __expf(logit[k + 2] - m); logit[k + 2] = c; e2 += c;
        float d = __expf(logit[k + 3] - m); logit[k + 3] = d; e3 += d;
    }
    const float inv = 1.f / ((e0 + e1) + (e2 + e3));
    float ent = 0.f;
#pragma unroll
    for (int k = 0; k < 32; k++) {
        float sv = logit[k] * inv;
        logit[k] = sv;
        ent += sv * __logf(sv + EPS);
    }
    float* so = s_out + n * 32;
#pragma unroll
    for (int k4 = 0; k4 < 8; k4++)
        *(float4*)(so + 4 * k4) = make_float4(logit[4 * k4], logit[4 * k4 + 1],
                                              logit[4 * k4 + 2], logit[4 * k4 + 3]);
    // wave-level reduce then one atomic per wave
#pragma unroll
    for (int off = 32; off > 0; off >>= 1) ent += __shfl_down(ent, off, 64);
    if ((threadIdx.x & 63) == 0) atomicAdd(ent_acc, ent);
}

// pooled outer product, feature-split: thread (k, fg) owns features fg*8..fg*8+7
// (+ one extra for fg<4). Per-block partial tile -> plain stores (NO atomics in
// the common path); only mid-block batch boundaries flush via atomics (rare).
__global__ void pool_k(const float* __restrict__ s,
                       const float* __restrict__ x,
                       const float* __restrict__ pos,
                       const int* __restrict__ batch,
                       float* __restrict__ bacc,
                       float* __restrict__ part,
                       int* __restrict__ tags,
                       int npb) {
    const int t = threadIdx.x;
    const int k = t & 31;
    const int fg = t >> 5;              // 0..7
    const int base = blockIdx.x * npb;
    float acc[8];
    float accx = 0.f;                   // fg==0: px, 1: py, 2: |p|^2, 3: sum
#pragma unroll
    for (int f = 0; f < 8; f++) acc[f] = 0.f;
    int cur_b = batch[base];
#pragma unroll 2
    for (int n = base; n < base + npb; n++) {
        const int b = batch[n];         // block-uniform scalar load
        if (b != cur_b) {               // uniform, rare (batch sorted, ~15 blocks total)
            float* dst = bacc + (cur_b * 32 + k) * FP;
#pragma unroll
            for (int f = 0; f < 8; f++) { atomicAdd(dst + fg * 8 + f, acc[f]); acc[f] = 0.f; }
            if (fg < 4) { atomicAdd(dst + 64 + fg, accx); accx = 0.f; }
            cur_b = b;
        }
        const float sv = s[n * 32 + k]; // coalesced across the wave
        const float4 v0 = *(const float4*)(x + n * 64 + fg * 8);      // broadcast per fg
        const float4 v1 = *(const float4*)(x + n * 64 + fg * 8 + 4);
        acc[0] = fmaf(sv, v0.x, acc[0]);
        acc[1] = fmaf(sv, v0.y, acc[1]);
        acc[2] = fmaf(sv, v0.z, acc[2]);
        acc[3] = fmaf(sv, v0.w, acc[3]);
        acc[4] = fmaf(sv, v1.x, acc[4]);
        acc[5] = fmaf(sv, v1.y, acc[5]);
        acc[6] = fmaf(sv, v1.z, acc[6]);
        acc[7] = fmaf(sv, v1.w, acc[7]);
        if (fg < 4) {                   // wave-uniform branch
            float2 p = *(const float2*)(pos + n * 2);                 // broadcast
            float e = (fg == 0) ? p.x : (fg == 1) ? p.y
                    : (fg == 2) ? (p.x * p.x + p.y * p.y) : 1.f;
            accx = fmaf(sv, e, accx);
        }
    }
    // plain coalesced partial store: layout part[blk][f*32 + k]
    float* pp = part + (size_t)blockIdx.x * CELLS;
#pragma unroll
    for (int f = 0; f < 8; f++) pp[(fg * 8 + f) * 32 + k] = acc[f];
    if (fg < 4) pp[(64 + fg) * 32 + k] = accx;
    if (t == 0) tags[blockIdx.x] = cur_b;
}

// one thread per (b,k,f) cell. tags[] is NON-DECREASING (batch sorted, each
// partial tile belongs wholly to its end-tag) -> binary-search the tag range
// for b and read only ~nblk/16 tiles instead of scanning all of them.
__global__ void reduce_k(const float* __restrict__ part,
                         const int* __restrict__ tags,
                         float* __restrict__ bacc,
                         float* __restrict__ outp,
                         int nblk) {
    const int b = blockIdx.x;                   // 0..15
    const int cell = blockIdx.y * 256 + threadIdx.x;
    if (cell >= CELLS) return;
    const int k = cell & 31, f = cell >> 5;
    int lo = 0, hi = nblk;                      // lo = first tag >= b
    while (lo < hi) { int mid = (lo + hi) >> 1; if (tags[mid] < b) lo = mid + 1; else hi = mid; }
    int lo2 = lo, hi2 = nblk;                   // lo2..: first tag >= b+1
    while (lo2 < hi2) { int mid = (lo2 + hi2) >> 1; if (tags[mid] < b + 1) lo2 = mid + 1; else hi2 = mid; }
    float v = 0.f;
    for (int blk = lo; blk < lo2; blk++)        // coalesced: cells contiguous per blk
        v += part[(size_t)blk * CELLS + cell];
    const int idx = (b * 32 + k) * FP + f;
    const float tot = bacc[idx] + v;            // + boundary flushes
    bacc[idx] = tot;
    if (f < 64) outp[OUT_OUT + ((b * 32 + k) << 6) + f] = tot;
}

// single block: mu + all six scalars
__global__ void fin_k(const float* __restrict__ ws,
                      const float* __restrict__ amask,
                      float* __restrict__ outp) {
    const int t = threadIdx.x;
    const float* bacc = ws + WS_BACC;
    __shared__ float mu_s[BB * KK * 2];
    for (int idx = t; idx < BB * KK * 2; idx += 256) {
        int bk = idx >> 1, d = idx & 1;
        float v = bacc[bk * FP + 64 + d] / (bacc[bk * FP + 67] + EPS);
        mu_s[idx] = v;
        outp[OUT_MU + idx] = v;
    }
    __shared__ float kred[32][4];
    if (t < 32) {
        float S = 0, px = 0, py = 0, sq = 0;
        for (int b = 0; b < 16; b++) {
            const float* pp = bacc + (b * 32 + t) * FP;
            S += pp[67]; px += pp[64]; py += pp[65]; sq += pp[66];
        }
        float avg = S / (float)NN;
        float am = amask[t];
        float ssum = S + EPS;
        float mx = px / ssum, my = py / ssum;
        kred[t][0] = avg * __logf(avg + EPS);          // diversity term
        kred[t][1] = fabsf(avg * (1.f - am));          // pruning term
        kred[t][2] = sq / ssum - mx * mx - my * my;    // spatial var
        kred[t][3] = am;                               // sparsity term
    }
    __syncthreads();
    float sep = 0.f;
    for (int idx = t; idx < BB * KK * KK; idx += 256) {
        int b = idx >> 10, i = (idx >> 5) & 31, j = idx & 31;
        if (i != j) {
            float dx = mu_s[(b * 32 + i) * 2 + 0] - mu_s[(b * 32 + j) * 2 + 0];
            float dy = mu_s[(b * 32 + i) * 2 + 1] - mu_s[(b * 32 + j) * 2 + 1];
            sep += 1.f / (dx * dx + dy * dy + 1.f);
        }
    }
    __shared__ float red[256];
    red[t] = sep;
    __syncthreads();
    for (int s2 = 128; s2 > 0; s2 >>= 1) {
        if (t < s2) red[t] += red[t + s2];
        __syncthreads();
    }
    if (t == 0) {
        float div = 0, pru = 0, spa = 0, spar = 0;
        for (int kq = 0; kq < 32; kq++) {
            div += kred[kq][0]; pru += kred[kq][1];
            spa += kred[kq][2]; spar += kred[kq][3];
        }
        outp[OUT_SCAL + 0] = -ws[WS_ENT] / (float)NN;        // entropy
        outp[OUT_SCAL + 1] = div;                            // diversity
        outp[OUT_SCAL + 2] = spa / 32.f;                     // spatial
        outp[OUT_SCAL + 3] = pru / 32.f;                     // pruning
        outp[OUT_SCAL + 4] = spar / 32.f;                    // sparsity
        outp[OUT_SCAL + 5] = red[0] / (32.f * 31.f + EPS);   // separation
    }
}

extern "C" void kernel_launch(void* const* d_in, const int* in_sizes, int n_in,
                              void* d_out, int out_size, void* d_ws, size_t ws_size,
                              hipStream_t stream) {
    const float* x       = (const float*)d_in[0];
    const int*   batch   = (const int*)d_in[1];
    const float* pos     = (const float*)d_in[2];
    const float* u       = (const float*)d_in[3];
    const float* W1      = (const float*)d_in[4];
    const float* b1      = (const float*)d_in[5];
    const float* W2      = (const float*)d_in[6];
    const float* b2      = (const float*)d_in[7];
    const float* scaling = (const float*)d_in[8];
    const float* amask   = (const float*)d_in[9];
    float* outp = (float*)d_out;
    float* ws   = (float*)d_ws;

    // choose nodes-per-block so the partial buffer fits ws (prefers 1024 blocks)
    int npb = 128;
    while (npb < NN &&
           ws_size < ((size_t)WS_PART + (size_t)(NN / npb) * CELLS) * sizeof(float))
        npb <<= 1;
    const int nblk = NN / npb;

    hipMemsetAsync(ws, 0, (size_t)(WS_BACC + WS_BACC_SZ) * sizeof(float), stream);
    prep_k<<<16, 256, 0, stream>>>(W1, ws);
    node_k<<<NN / 256, 256, 0, stream>>>(x, u, ws + WS_W1T, b1, W2, b2, scaling, amask,
                                         outp + OUT_S, ws + WS_ENT);
    pool_k<<<nblk, 256, 0, stream>>>(outp + OUT_S, x, pos, batch,
                                     ws + WS_BACC, ws + WS_PART, (int*)(ws + WS_TAG), npb);
    reduce_k<<<dim3(BB, (CELLS + 255) / 256), 256, 0, stream>>>(
        ws + WS_PART, (const int*)(ws + WS_TAG), ws + WS_BACC, outp, nblk);
    fin_k<<<1, 256, 0, stream>>>(ws, amask, outp);
}